// Round 4
// baseline (145.153 us; speedup 1.0000x reference)
//
#include <hip/hip_runtime.h>

#define NSAMP 4096
#define SS0 3969   // 63*63
#define SS1 961    // 31*31

// One kernel does everything:
//   per-sample loss_i = sum_levels (A/T^2 - 2B/T + C) / (S*S)
//   T=sum c, A=sum c^2, B=sum c*h, C=(sum gy^2)(sum gx^2), h=gy[y]*gx[x]
// then the last block to finish reduces all 4096 partials deterministically.
__global__ __launch_bounds__(256) void heat_one_kernel(
    const float* __restrict__ cls0,
    const float* __restrict__ cls1,
    const float* __restrict__ gt,
    float* __restrict__ partial,         // ws: NSAMP floats
    unsigned int* __restrict__ counter,  // ws: 1 uint after partials (memset to 0 per call)
    float* __restrict__ out)
{
    __shared__ float g0x[63], g0y[63], g1x[31], g1y[31];
    __shared__ float sg[4];        // {sum g0x^2, sum g0y^2, sum g1x^2, sum g1y^2}
    __shared__ float red[4][6];
    __shared__ int bLast;

    const int sid  = blockIdx.x;
    const int tid  = threadIdx.x;
    const int lane = tid & 63;
    const int wid  = tid >> 6;

    const float4 bb = *reinterpret_cast<const float4*>(gt + (size_t)sid * 4);
    const float cx = 0.5f * (bb.x + bb.z) - 64.0f;
    const float cy = 0.5f * (bb.y + bb.w) - 64.0f;
    const float bw = bb.z - bb.x;
    const float bh = bb.w - bb.y;

    // Wave w builds one Gaussian table + its square-sum (for C).
    {
        const float invs  = (wid < 2) ? 0.25f : 0.125f;
        const bool  horiz = !(wid & 1);
        const int   len   = (wid < 2) ? 63 : 31;
        float* tbl = (wid == 0) ? g0x : (wid == 1) ? g0y : (wid == 2) ? g1x : g1y;
        const float mu  = (horiz ? cx : cy) * invs;
        const float is  = 1.0f / (0.2f * (horiz ? bw : bh) * invs);
        const float amp = 0.39894228040143267794f * is;
        float v = 0.0f;
        if (lane < len) {
            float d = ((float)lane - mu) * is;
            v = amp * __expf(-0.5f * d * d);
            tbl[lane] = v;
        }
        float v2 = v * v;
        #pragma unroll
        for (int off = 32; off > 0; off >>= 1) v2 += __shfl_down(v2, off);
        if (lane == 0) sg[wid] = v2;
    }
    __syncthreads();

    // ---- level 0: flat float4 stream with alignment peel ----
    const float* p0 = cls0 + (size_t)sid * SS0;
    const int a0  = (int)(((16u - (unsigned)((uintptr_t)p0 & 15)) & 15u) >> 2);
    const int nv0 = (SS0 - a0) >> 2;
    const float4* __restrict__ v0 = reinterpret_cast<const float4*>(p0 + a0);

    float T0 = 0.0f, A0 = 0.0f, B0 = 0.0f;
    #pragma unroll 2
    for (int k = tid; k < nv0; k += 256) {
        const float4 v = v0[k];
        const int e = a0 + 4 * k;
        const int y = e / 63;               // constexpr magic-mul
        const int x = e - y * 63;
        int x1 = x + 1, y1 = y; if (x1 >= 63) { x1 -= 63; ++y1; }
        int x2 = x + 2, y2 = y; if (x2 >= 63) { x2 -= 63; ++y2; }
        int x3 = x + 3, y3 = y; if (x3 >= 63) { x3 -= 63; ++y3; }
        { float c = v.x; float h = g0y[y]  * g0x[x];  T0 += c; A0 = fmaf(c, c, A0); B0 = fmaf(c, h, B0); }
        { float c = v.y; float h = g0y[y1] * g0x[x1]; T0 += c; A0 = fmaf(c, c, A0); B0 = fmaf(c, h, B0); }
        { float c = v.z; float h = g0y[y2] * g0x[x2]; T0 += c; A0 = fmaf(c, c, A0); B0 = fmaf(c, h, B0); }
        { float c = v.w; float h = g0y[y3] * g0x[x3]; T0 += c; A0 = fmaf(c, c, A0); B0 = fmaf(c, h, B0); }
    }
    if (tid == 255) {  // peel + tail (<= 6 elements)
        for (int e = 0; e < a0; ++e) {
            float c = p0[e]; int y = e / 63; int x = e - y * 63;
            float h = g0y[y] * g0x[x];
            T0 += c; A0 = fmaf(c, c, A0); B0 = fmaf(c, h, B0);
        }
        for (int e = a0 + 4 * nv0; e < SS0; ++e) {
            float c = p0[e]; int y = e / 63; int x = e - y * 63;
            float h = g0y[y] * g0x[x];
            T0 += c; A0 = fmaf(c, c, A0); B0 = fmaf(c, h, B0);
        }
    }

    // ---- level 1: same scheme, /31 ----
    const float* p1 = cls1 + (size_t)sid * SS1;
    const int a1  = (int)(((16u - (unsigned)((uintptr_t)p1 & 15)) & 15u) >> 2);
    const int nv1 = (SS1 - a1) >> 2;
    const float4* __restrict__ v1 = reinterpret_cast<const float4*>(p1 + a1);

    float T1 = 0.0f, A1 = 0.0f, B1 = 0.0f;
    for (int k = tid; k < nv1; k += 256) {
        const float4 v = v1[k];
        const int e = a1 + 4 * k;
        const int y = e / 31;
        const int x = e - y * 31;
        int x1 = x + 1, y1 = y; if (x1 >= 31) { x1 -= 31; ++y1; }
        int x2 = x + 2, y2 = y; if (x2 >= 31) { x2 -= 31; ++y2; }
        int x3 = x + 3, y3 = y; if (x3 >= 31) { x3 -= 31; ++y3; }
        { float c = v.x; float h = g1y[y]  * g1x[x];  T1 += c; A1 = fmaf(c, c, A1); B1 = fmaf(c, h, B1); }
        { float c = v.y; float h = g1y[y1] * g1x[x1]; T1 += c; A1 = fmaf(c, c, A1); B1 = fmaf(c, h, B1); }
        { float c = v.z; float h = g1y[y2] * g1x[x2]; T1 += c; A1 = fmaf(c, c, A1); B1 = fmaf(c, h, B1); }
        { float c = v.w; float h = g1y[y3] * g1x[x3]; T1 += c; A1 = fmaf(c, c, A1); B1 = fmaf(c, h, B1); }
    }
    if (tid == 254) {  // peel + tail
        for (int e = 0; e < a1; ++e) {
            float c = p1[e]; int y = e / 31; int x = e - y * 31;
            float h = g1y[y] * g1x[x];
            T1 += c; A1 = fmaf(c, c, A1); B1 = fmaf(c, h, B1);
        }
        for (int e = a1 + 4 * nv1; e < SS1; ++e) {
            float c = p1[e]; int y = e / 31; int x = e - y * 31;
            float h = g1y[y] * g1x[x];
            T1 += c; A1 = fmaf(c, c, A1); B1 = fmaf(c, h, B1);
        }
    }

    // ---- block reduction ----
    #pragma unroll
    for (int off = 32; off > 0; off >>= 1) {
        T0 += __shfl_down(T0, off); A0 += __shfl_down(A0, off); B0 += __shfl_down(B0, off);
        T1 += __shfl_down(T1, off); A1 += __shfl_down(A1, off); B1 += __shfl_down(B1, off);
    }
    if (lane == 0) {
        red[wid][0] = T0; red[wid][1] = A0; red[wid][2] = B0;
        red[wid][3] = T1; red[wid][4] = A1; red[wid][5] = B1;
    }
    __syncthreads();
    if (tid == 0) {
        float t0 = 0, a_0 = 0, b0 = 0, t1 = 0, a_1 = 0, b1 = 0;
        #pragma unroll
        for (int w = 0; w < 4; ++w) {
            t0 += red[w][0]; a_0 += red[w][1]; b0 += red[w][2];
            t1 += red[w][3]; a_1 += red[w][4]; b1 += red[w][5];
        }
        const float C0 = sg[0] * sg[1];
        const float C1 = sg[2] * sg[3];
        const float i0 = 1.0f / t0;
        const float i1 = 1.0f / t1;
        const float l0 = (fmaf(a_0 * i0, i0, -2.0f * b0 * i0) + C0) * (1.0f / 3969.0f);
        const float l1 = (fmaf(a_1 * i1, i1, -2.0f * b1 * i1) + C1) * (1.0f / 961.0f);
        const float loss = l0 + l1;
        // publish partial at agent (device) scope, then count completion
        __hip_atomic_store(&partial[sid], loss, __ATOMIC_RELEASE, __HIP_MEMORY_SCOPE_AGENT);
        __threadfence();
        unsigned old = atomicAdd(counter, 1u);
        bLast = (old == NSAMP - 1) ? 1 : 0;
    }
    __syncthreads();

    // ---- last block: deterministic fixed-order final reduction ----
    if (bLast) {
        __threadfence();  // acquire side
        float s = 0.0f;
        #pragma unroll
        for (int i = 0; i < NSAMP / 256; ++i)
            s += __hip_atomic_load(&partial[tid + i * 256], __ATOMIC_RELAXED, __HIP_MEMORY_SCOPE_AGENT);
        #pragma unroll
        for (int off = 32; off > 0; off >>= 1) s += __shfl_down(s, off);
        __syncthreads();               // red[] reuse
        if (lane == 0) red[wid][0] = s;
        __syncthreads();
        if (tid == 0) out[0] = (red[0][0] + red[1][0]) + (red[2][0] + red[3][0]);
    }
}

extern "C" void kernel_launch(void* const* d_in, const int* in_sizes, int n_in,
                              void* d_out, int out_size, void* d_ws, size_t ws_size,
                              hipStream_t stream) {
    // inputs: 0=cls0 (N,1,63,63), 1=reg0 (unused), 2=cls1 (N,1,31,31),
    //         3=reg1 (unused), 4=gt_bbox (N,4)
    const float* cls0 = (const float*)d_in[0];
    const float* cls1 = (const float*)d_in[2];
    const float* gt   = (const float*)d_in[4];
    float* out = (float*)d_out;
    float* partial = (float*)d_ws;                                  // 16 KiB
    unsigned int* counter = (unsigned int*)((char*)d_ws + NSAMP * 4);

    hipMemsetAsync(counter, 0, sizeof(unsigned int), stream);       // per-call reset
    heat_one_kernel<<<NSAMP, 256, 0, stream>>>(cls0, cls1, gt, partial, counter, out);
}

// Round 5
// 24.946 us; speedup vs baseline: 5.8187x; 5.8187x over previous
//
#include <hip/hip_runtime.h>

#define NSAMP 4096
#define SS0 3969   // 63*63
#define SS1 961    // 31*31

typedef float f4v __attribute__((ext_vector_type(4), aligned(4)));

// Per-sample loss over both pyramid levels, one block per sample.
// loss = sum_levels (A/T^2 - 2B/T + C) / (S*S)
//   T = sum c, A = sum c^2, B = sum c*h, C = (sum gy^2)(sum gx^2)
// All global loads are 16B/lane float4 (align-4 ok: global_load_dwordx4).
__global__ __launch_bounds__(256) void heat_main_kernel(
    const float* __restrict__ cls0,   // (NSAMP, 63*63)
    const float* __restrict__ cls1,   // (NSAMP, 31*31)
    const float* __restrict__ gt,     // (NSAMP, 4)
    float* __restrict__ partial)      // (NSAMP,)
{
    __shared__ float g0x[64], g0y[64], g1x[32], g1y[32];
    __shared__ float sg[4];    // {sum g0x^2, sum g0y^2, sum g1x^2, sum g1y^2}
    __shared__ float red[4][6];

    const int sid  = blockIdx.x;
    const int tid  = threadIdx.x;
    const int lane = tid & 63;
    const int wid  = tid >> 6;

    const float4 bb = *reinterpret_cast<const float4*>(gt + (size_t)sid * 4);
    const float cx = 0.5f * (bb.x + bb.z) - 64.0f;
    const float cy = 0.5f * (bb.y + bb.w) - 64.0f;
    const float bw = bb.z - bb.x;
    const float bh = bb.w - bb.y;

    // Wave w builds one Gaussian table (zero-filled to pow2 size) + square-sum.
    {
        const float invs  = (wid < 2) ? 0.25f : 0.125f;
        const bool  horiz = !(wid & 1);
        const int   len   = (wid < 2) ? 63 : 31;
        const int   tsz   = (wid < 2) ? 64 : 32;
        float* tbl = (wid == 0) ? g0x : (wid == 1) ? g0y : (wid == 2) ? g1x : g1y;
        const float mu  = (horiz ? cx : cy) * invs;
        const float is  = 1.0f / (0.2f * (horiz ? bw : bh) * invs);
        const float amp = 0.39894228040143267794f * is;
        float v = 0.0f;
        if (lane < len) {
            float d = ((float)lane - mu) * is;
            v = amp * __expf(-0.5f * d * d);
        }
        if (lane < tsz) tbl[lane] = v;   // zero beyond len (masks col 63 / 31)
        float v2 = v * v;
        #pragma unroll
        for (int off = 32; off > 0; off >>= 1) v2 += __shfl_down(v2, off);
        if (lane == 0) sg[wid] = v2;
    }
    __syncthreads();

    // ---- level 0: 63x63. Wave = 4 rows x 64 cols; lane = (r=lane>>4, g=lane&15).
    // 4 iterations cover rows 0..62 (y==63 predicated off). Col 63 masked.
    const float* __restrict__ p0 = cls0 + (size_t)sid * SS0;
    const int g = lane & 15;
    const int r = lane >> 4;
    const float keep3_0 = (g < 15) ? 1.0f : 0.0f;
    const float gx00 = g0x[4 * g], gx01 = g0x[4 * g + 1];
    const float gx02 = g0x[4 * g + 2], gx03 = g0x[4 * g + 3];

    float T0 = 0.0f, A0 = 0.0f;
    float Bc0 = 0.0f, Bc1 = 0.0f, Bc2 = 0.0f, Bc3 = 0.0f;
    #pragma unroll
    for (int it = 0; it < 4; ++it) {
        const int y = 16 * it + 4 * wid + r;
        if (y < 63) {
            // lane (y==62,g==15) would read 4B past the sample: shift-load e-1.
            const bool danger = (y == 62) && (g == 15);
            const int e = y * 63 + 4 * g - (danger ? 1 : 0);
            const f4v v = *reinterpret_cast<const f4v*>(p0 + e);
            float c0 = danger ? v.y : v.x;
            float c1 = danger ? v.z : v.y;
            float c2 = danger ? v.w : v.z;
            float c3 = (danger ? 0.0f : v.w) * keep3_0;
            const float gyv = g0y[y];
            T0 += (c0 + c1) + (c2 + c3);
            A0 = fmaf(c0, c0, A0); A0 = fmaf(c1, c1, A0);
            A0 = fmaf(c2, c2, A0); A0 = fmaf(c3, c3, A0);
            Bc0 = fmaf(c0, gyv, Bc0); Bc1 = fmaf(c1, gyv, Bc1);
            Bc2 = fmaf(c2, gyv, Bc2); Bc3 = fmaf(c3, gyv, Bc3);
        }
    }
    float B0 = (Bc0 * gx00 + Bc1 * gx01) + (Bc2 * gx02 + Bc3 * gx03);

    // ---- level 1: 31x31. Wave = 8 rows x 32 cols; ONE iteration covers all rows.
    const float* __restrict__ p1 = cls1 + (size_t)sid * SS1;
    float T1 = 0.0f, A1 = 0.0f, B1 = 0.0f;
    {
        const int g1 = lane & 7;
        const int y1 = 8 * wid + (lane >> 3);
        if (y1 < 31) {
            const float keep3_1 = (g1 < 7) ? 1.0f : 0.0f;
            const bool danger = (y1 == 30) && (g1 == 7);
            const int e = y1 * 31 + 4 * g1 - (danger ? 1 : 0);
            const f4v v = *reinterpret_cast<const f4v*>(p1 + e);
            float c0 = danger ? v.y : v.x;
            float c1 = danger ? v.z : v.y;
            float c2 = danger ? v.w : v.z;
            float c3 = (danger ? 0.0f : v.w) * keep3_1;
            const float gyv = g1y[y1];
            const float gx10 = g1x[4 * g1],     gx11 = g1x[4 * g1 + 1];
            const float gx12 = g1x[4 * g1 + 2], gx13 = g1x[4 * g1 + 3];
            T1 = (c0 + c1) + (c2 + c3);
            A1 = fmaf(c0, c0, fmaf(c1, c1, fmaf(c2, c2, c3 * c3)));
            B1 = gyv * ((c0 * gx10 + c1 * gx11) + (c2 * gx12 + c3 * gx13));
        }
    }

    // ---- block reduction of the six partials ----
    #pragma unroll
    for (int off = 32; off > 0; off >>= 1) {
        T0 += __shfl_down(T0, off); A0 += __shfl_down(A0, off); B0 += __shfl_down(B0, off);
        T1 += __shfl_down(T1, off); A1 += __shfl_down(A1, off); B1 += __shfl_down(B1, off);
    }
    if (lane == 0) {
        red[wid][0] = T0; red[wid][1] = A0; red[wid][2] = B0;
        red[wid][3] = T1; red[wid][4] = A1; red[wid][5] = B1;
    }
    __syncthreads();
    if (tid == 0) {
        float t0 = 0, a0 = 0, b0 = 0, t1 = 0, a1 = 0, b1 = 0;
        #pragma unroll
        for (int w = 0; w < 4; ++w) {
            t0 += red[w][0]; a0 += red[w][1]; b0 += red[w][2];
            t1 += red[w][3]; a1 += red[w][4]; b1 += red[w][5];
        }
        const float C0 = sg[0] * sg[1];
        const float C1 = sg[2] * sg[3];
        const float i0 = 1.0f / t0;
        const float i1 = 1.0f / t1;
        const float l0 = (fmaf(a0 * i0, i0, -2.0f * b0 * i0) + C0) * (1.0f / 3969.0f);
        const float l1 = (fmaf(a1 * i1, i1, -2.0f * b1 * i1) + C1) * (1.0f / 961.0f);
        partial[sid] = l0 + l1;
    }
}

// Deterministic fixed-order final reduction of NSAMP partials (float4 loads).
__global__ __launch_bounds__(1024) void heat_final_kernel(
    const float* __restrict__ partial, float* __restrict__ out)
{
    __shared__ float red[16];
    const int tid = threadIdx.x;
    const float4 v = reinterpret_cast<const float4*>(partial)[tid];  // 1024*4 = 4096
    float s = (v.x + v.y) + (v.z + v.w);
    #pragma unroll
    for (int off = 32; off > 0; off >>= 1) s += __shfl_down(s, off);
    if ((tid & 63) == 0) red[tid >> 6] = s;
    __syncthreads();
    if (tid == 0) {
        float t = 0.0f;
        #pragma unroll
        for (int w = 0; w < 16; ++w) t += red[w];
        out[0] = t;
    }
}

extern "C" void kernel_launch(void* const* d_in, const int* in_sizes, int n_in,
                              void* d_out, int out_size, void* d_ws, size_t ws_size,
                              hipStream_t stream) {
    // inputs: 0=cls0 (N,1,63,63), 1=reg0 (unused), 2=cls1 (N,1,31,31),
    //         3=reg1 (unused), 4=gt_bbox (N,4)
    const float* cls0 = (const float*)d_in[0];
    const float* cls1 = (const float*)d_in[2];
    const float* gt   = (const float*)d_in[4];
    float* out = (float*)d_out;
    float* ws  = (float*)d_ws;   // NSAMP floats = 16 KiB

    heat_main_kernel<<<NSAMP, 256, 0, stream>>>(cls0, cls1, gt, ws);
    heat_final_kernel<<<1, 1024, 0, stream>>>(ws, out);
}

// Round 7
// 20.706 us; speedup vs baseline: 7.0103x; 1.2048x over previous
//
#include <hip/hip_runtime.h>

#define NSAMP 4096
#define SS0 3969   // 63*63
#define SS1 961    // 31*31

typedef float f4v __attribute__((ext_vector_type(4), aligned(4)));

// Per-sample loss over both pyramid levels, one block per sample.
// loss = sum_levels (A/T^2 - 2B/T + C) / (S*S)
//   T = sum c, A = sum c^2, B = sum c*h, C = (sum gy^2)(sum gx^2)
// Structure: issue ALL global loads up-front (branchless, clamped addresses),
// build Gaussian tables while loads are in flight, then consume.
__global__ __launch_bounds__(256) void heat_main_kernel(
    const float* __restrict__ cls0,   // (NSAMP, 63*63)
    const float* __restrict__ cls1,   // (NSAMP, 31*31)
    const float* __restrict__ gt,     // (NSAMP, 4)
    float* __restrict__ partial)      // (NSAMP,)
{
    __shared__ float g0x[64], g0y[64], g1x[32], g1y[32];
    __shared__ float sg[4];    // {sum g0x^2, sum g0y^2, sum g1x^2, sum g1y^2}
    __shared__ float red[4][6];

    const int sid  = blockIdx.x;
    const int tid  = threadIdx.x;
    const int lane = tid & 63;
    const int wid  = tid >> 6;

    // ---------- phase 1: issue all global loads (1 + 4 + 1 per thread) ----------
    const float4 bb = *reinterpret_cast<const float4*>(gt + (size_t)sid * 4);

    const float* __restrict__ p0 = cls0 + (size_t)sid * SS0;
    const float* __restrict__ p1 = cls1 + (size_t)sid * SS1;

    // level 0: wave = 4 rows x 64 cols; lane = (r=lane>>4, g=lane&15)
    const int g = lane & 15;
    const int r = lane >> 4;
    int  yv[4]; bool dg0[4]; f4v L0[4];
    #pragma unroll
    for (int it = 0; it < 4; ++it) {
        const int yy = 16 * it + 4 * wid + r;        // 0..63 (63 masked later)
        const int yc = (yy > 62) ? 62 : yy;          // clamp: load stays in-bounds
        const bool danger = (yc == 62) & (g == 15);  // would touch elem 3969
        const int e = yc * 63 + 4 * g - (danger ? 1 : 0);
        L0[it] = *reinterpret_cast<const f4v*>(p0 + e);
        yv[it] = yy; dg0[it] = danger;
    }
    // level 1: wave = 8 rows x 32 cols
    const int g1  = lane & 7;
    const int y1  = 8 * wid + (lane >> 3);           // 0..31 (31 masked later)
    const int yc1 = (y1 > 30) ? 30 : y1;
    const bool dg1 = (yc1 == 30) & (g1 == 7);
    const f4v L1 = *reinterpret_cast<const f4v*>(p1 + yc1 * 31 + 4 * g1 - (dg1 ? 1 : 0));

    // ---------- phase 2: Gaussian tables (overlaps load latency) ----------
    {
        const float cx = 0.5f * (bb.x + bb.z) - 64.0f;
        const float cy = 0.5f * (bb.y + bb.w) - 64.0f;
        const float bw = bb.z - bb.x;
        const float bh = bb.w - bb.y;
        const float invs  = (wid < 2) ? 0.25f : 0.125f;
        const bool  horiz = !(wid & 1);
        const int   len   = (wid < 2) ? 63 : 31;
        const int   tsz   = (wid < 2) ? 64 : 32;
        float* tbl = (wid == 0) ? g0x : (wid == 1) ? g0y : (wid == 2) ? g1x : g1y;
        const float mu  = (horiz ? cx : cy) * invs;
        const float is  = 1.0f / (0.2f * (horiz ? bw : bh) * invs);
        const float amp = 0.39894228040143267794f * is;
        float v = 0.0f;
        if (lane < len) {
            float d = ((float)lane - mu) * is;
            v = amp * __expf(-0.5f * d * d);
        }
        if (lane < tsz) tbl[lane] = v;   // zero beyond len
        float v2 = v * v;
        #pragma unroll
        for (int off = 32; off > 0; off >>= 1) v2 += __shfl_down(v2, off);
        if (lane == 0) sg[wid] = v2;
    }
    __syncthreads();

    // ---------- phase 3: consume ----------
    const float keep3_0 = (g < 15) ? 1.0f : 0.0f;
    const float gx00 = g0x[4 * g], gx01 = g0x[4 * g + 1];
    const float gx02 = g0x[4 * g + 2], gx03 = g0x[4 * g + 3];

    float T0 = 0.0f, A0 = 0.0f;
    float Bc0 = 0.0f, Bc1 = 0.0f, Bc2 = 0.0f, Bc3 = 0.0f;
    #pragma unroll
    for (int it = 0; it < 4; ++it) {
        const float m = (yv[it] < 63) ? 1.0f : 0.0f;     // row mask (branchless)
        const int  yc = (yv[it] > 62) ? 62 : yv[it];
        const f4v  v  = L0[it];
        const bool d  = dg0[it];
        const float c0 = (d ? v.y : v.x) * m;
        const float c1 = (d ? v.z : v.y) * m;
        const float c2 = (d ? v.w : v.z) * m;
        const float c3 = (d ? 0.0f : v.w) * keep3_0 * m;
        const float gyv = g0y[yc];
        T0 += (c0 + c1) + (c2 + c3);
        A0 = fmaf(c0, c0, A0); A0 = fmaf(c1, c1, A0);
        A0 = fmaf(c2, c2, A0); A0 = fmaf(c3, c3, A0);
        Bc0 = fmaf(c0, gyv, Bc0); Bc1 = fmaf(c1, gyv, Bc1);
        Bc2 = fmaf(c2, gyv, Bc2); Bc3 = fmaf(c3, gyv, Bc3);
    }
    float B0 = (Bc0 * gx00 + Bc1 * gx01) + (Bc2 * gx02 + Bc3 * gx03);

    float T1 = 0.0f, A1 = 0.0f, B1 = 0.0f;
    {
        const float m1 = (y1 < 31) ? 1.0f : 0.0f;
        const float keep3_1 = (g1 < 7) ? 1.0f : 0.0f;
        const float c0 = (dg1 ? L1.y : L1.x) * m1;
        const float c1 = (dg1 ? L1.z : L1.y) * m1;
        const float c2 = (dg1 ? L1.w : L1.z) * m1;
        const float c3 = (dg1 ? 0.0f : L1.w) * keep3_1 * m1;
        const float gyv = g1y[yc1];
        const float gx10 = g1x[4 * g1],     gx11 = g1x[4 * g1 + 1];
        const float gx12 = g1x[4 * g1 + 2], gx13 = g1x[4 * g1 + 3];
        T1 = (c0 + c1) + (c2 + c3);
        A1 = fmaf(c0, c0, fmaf(c1, c1, fmaf(c2, c2, c3 * c3)));
        B1 = gyv * ((c0 * gx10 + c1 * gx11) + (c2 * gx12 + c3 * gx13));
    }

    // ---------- block reduction ----------
    #pragma unroll
    for (int off = 32; off > 0; off >>= 1) {
        T0 += __shfl_down(T0, off); A0 += __shfl_down(A0, off); B0 += __shfl_down(B0, off);
        T1 += __shfl_down(T1, off); A1 += __shfl_down(A1, off); B1 += __shfl_down(B1, off);
    }
    if (lane == 0) {
        red[wid][0] = T0; red[wid][1] = A0; red[wid][2] = B0;
        red[wid][3] = T1; red[wid][4] = A1; red[wid][5] = B1;
    }
    __syncthreads();
    if (tid == 0) {
        float t0 = 0, a0 = 0, b0 = 0, t1 = 0, a1 = 0, b1 = 0;
        #pragma unroll
        for (int w = 0; w < 4; ++w) {
            t0 += red[w][0]; a0 += red[w][1]; b0 += red[w][2];
            t1 += red[w][3]; a1 += red[w][4]; b1 += red[w][5];
        }
        const float C0 = sg[0] * sg[1];
        const float C1 = sg[2] * sg[3];
        const float i0 = 1.0f / t0;
        const float i1 = 1.0f / t1;
        const float l0 = (fmaf(a0 * i0, i0, -2.0f * b0 * i0) + C0) * (1.0f / 3969.0f);
        const float l1 = (fmaf(a1 * i1, i1, -2.0f * b1 * i1) + C1) * (1.0f / 961.0f);
        partial[sid] = l0 + l1;
    }
}

// Deterministic fixed-order final reduction of NSAMP partials (float4 loads).
__global__ __launch_bounds__(1024) void heat_final_kernel(
    const float* __restrict__ partial, float* __restrict__ out)
{
    __shared__ float red[16];
    const int tid = threadIdx.x;
    const float4 v = reinterpret_cast<const float4*>(partial)[tid];  // 1024*4 = 4096
    float s = (v.x + v.y) + (v.z + v.w);
    #pragma unroll
    for (int off = 32; off > 0; off >>= 1) s += __shfl_down(s, off);
    if ((tid & 63) == 0) red[tid >> 6] = s;
    __syncthreads();
    if (tid == 0) {
        float t = 0.0f;
        #pragma unroll
        for (int w = 0; w < 16; ++w) t += red[w];
        out[0] = t;
    }
}

extern "C" void kernel_launch(void* const* d_in, const int* in_sizes, int n_in,
                              void* d_out, int out_size, void* d_ws, size_t ws_size,
                              hipStream_t stream) {
    // inputs: 0=cls0 (N,1,63,63), 1=reg0 (unused), 2=cls1 (N,1,31,31),
    //         3=reg1 (unused), 4=gt_bbox (N,4)
    const float* cls0 = (const float*)d_in[0];
    const float* cls1 = (const float*)d_in[2];
    const float* gt   = (const float*)d_in[4];
    float* out = (float*)d_out;
    float* ws  = (float*)d_ws;   // NSAMP floats = 16 KiB

    heat_main_kernel<<<NSAMP, 256, 0, stream>>>(cls0, cls1, gt, ws);
    heat_final_kernel<<<1, 1024, 0, stream>>>(ws, out);
}